// Round 1
// baseline (610.196 us; speedup 1.0000x reference)
//
#include <hip/hip_runtime.h>
#include <math.h>

#define N_NODES 50000
#define DIM     128
#define N_EDGES 800000
#define N_UID   4096
#define NB      16
#define LN_EPS  1e-5f

// ---------- CSR build ----------
__global__ __launch_bounds__(256) void deg_kernel(const int* __restrict__ dst, int* __restrict__ cnt) {
    int e = blockIdx.x * 256 + threadIdx.x;
    if (e < N_EDGES) atomicAdd(&cnt[dst[e]], 1);
}

__global__ __launch_bounds__(256) void inv_kernel(const int* __restrict__ cnt, float* __restrict__ inv) {
    int n = blockIdx.x * 256 + threadIdx.x;
    if (n < N_NODES) inv[n] = 1.0f / (float)(cnt[n] + 1);
}

__global__ __launch_bounds__(256) void scan1(const int* __restrict__ cnt, int* __restrict__ off,
                                             int* __restrict__ bsum) {
    __shared__ int sh[256];
    int t = threadIdx.x;
    int i = blockIdx.x * 256 + t;
    int v = (i < N_NODES) ? cnt[i] : 0;
    sh[t] = v;
    __syncthreads();
    for (int o = 1; o < 256; o <<= 1) {
        int x = (t >= o) ? sh[t - o] : 0;
        __syncthreads();
        sh[t] += x;
        __syncthreads();
    }
    if (i < N_NODES) off[i] = sh[t] - v;   // exclusive
    if (t == 255) bsum[blockIdx.x] = sh[255];
}

__global__ __launch_bounds__(256) void scan2(const int* __restrict__ bsum, int* __restrict__ bpre, int nblk) {
    __shared__ int sh[256];
    int t = threadIdx.x;
    int v = (t < nblk) ? bsum[t] : 0;
    sh[t] = v;
    __syncthreads();
    for (int o = 1; o < 256; o <<= 1) {
        int x = (t >= o) ? sh[t - o] : 0;
        __syncthreads();
        sh[t] += x;
        __syncthreads();
    }
    if (t < nblk) bpre[t] = sh[t] - v;     // exclusive
}

__global__ __launch_bounds__(256) void scan3(int* __restrict__ off, const int* __restrict__ bpre,
                                             int* __restrict__ cur) {
    int i = blockIdx.x * 256 + threadIdx.x;
    if (i < N_NODES) {
        int o = off[i] + bpre[blockIdx.x];
        off[i] = o;
        cur[i] = o;
    }
    if (i == 0) off[N_NODES] = N_EDGES;
}

__global__ __launch_bounds__(256) void fill_kernel(const int* __restrict__ src, const int* __restrict__ dst,
                                                   int* __restrict__ cur, int* __restrict__ csr) {
    int e = blockIdx.x * 256 + threadIdx.x;
    if (e < N_EDGES) {
        int p = atomicAdd(&cur[dst[e]], 1);
        csr[p] = src[e];
    }
}

// ---------- fused layer: gather-aggregate + GEMM + LN + ELU ----------
// block = 128 threads, handles NB=16 nodes. 50000 = 16*3125 exactly.
__global__ __launch_bounds__(128) void layer_kernel(
    const float* __restrict__ fin, float* __restrict__ fout,
    const int* __restrict__ off, const int* __restrict__ csr,
    const float* __restrict__ inv,
    const float* __restrict__ W, const float* __restrict__ bias,
    const float* __restrict__ gamma, const float* __restrict__ beta)
{
    __shared__ float xs[NB][DIM];       // aggregated inputs
    __shared__ float ys[NB][DIM + 4];   // gemm outputs (padded rows)
    const int t = threadIdx.x;
    const int base = blockIdx.x * NB;

    // ---- phase 1: aggregate (neigh + self) * inv into xs ----
    {
        const int lane32 = t & 31;      // float4 index within row
        const int half   = t >> 5;      // 0..3
        for (int rep = 0; rep < 4; ++rep) {
            const int ns = rep * 4 + half;
            const int n  = base + ns;
            const float4* selfp = (const float4*)(fin + (size_t)n * DIM);
            float4 acc = selfp[lane32];
            const int e0 = off[n], e1 = off[n + 1];
            for (int e = e0; e < e1; ++e) {
                const int s = csr[e];
                const float4 v = ((const float4*)(fin + (size_t)s * DIM))[lane32];
                acc.x += v.x; acc.y += v.y; acc.z += v.z; acc.w += v.w;
            }
            const float iv = inv[n];
            acc.x *= iv; acc.y *= iv; acc.z *= iv; acc.w *= iv;
            ((float4*)xs[ns])[lane32] = acc;
        }
    }
    __syncthreads();

    // ---- phase 2: y[n][e] = dot(W[e,:], x[n,:]) + b[e], thread e = t ----
    {
        float acc[NB];
        const float bv = bias[t];
        #pragma unroll
        for (int j = 0; j < NB; ++j) acc[j] = bv;
        const float4* Wr = (const float4*)(W + (size_t)t * DIM);
        for (int k4 = 0; k4 < DIM / 4; ++k4) {
            const float4 w = Wr[k4];
            #pragma unroll
            for (int j = 0; j < NB; ++j) {
                const float4 xv = ((const float4*)xs[j])[k4];   // LDS broadcast
                acc[j] = fmaf(w.x, xv.x, acc[j]);
                acc[j] = fmaf(w.y, xv.y, acc[j]);
                acc[j] = fmaf(w.z, xv.z, acc[j]);
                acc[j] = fmaf(w.w, xv.w, acc[j]);
            }
        }
        #pragma unroll
        for (int j = 0; j < NB; ++j) ys[j][t] = acc[j];
    }
    __syncthreads();

    // ---- phase 3: LayerNorm + ELU; 8 threads per node, 16 dims each ----
    {
        const int n2  = t >> 3;          // node 0..15
        const int seg = t & 7;           // 0..7
        const float* yr = ys[n2] + seg * 16;
        const float4 v0 = *((const float4*)(yr + 0));
        const float4 v1 = *((const float4*)(yr + 4));
        const float4 v2 = *((const float4*)(yr + 8));
        const float4 v3 = *((const float4*)(yr + 12));
        float vs[16] = {v0.x, v0.y, v0.z, v0.w, v1.x, v1.y, v1.z, v1.w,
                        v2.x, v2.y, v2.z, v2.w, v3.x, v3.y, v3.z, v3.w};
        float s = 0.0f, s2 = 0.0f;
        #pragma unroll
        for (int j = 0; j < 16; ++j) { s += vs[j]; s2 += vs[j] * vs[j]; }
        #pragma unroll
        for (int m = 1; m < 8; m <<= 1) {
            s  += __shfl_xor(s,  m);
            s2 += __shfl_xor(s2, m);
        }
        const float mu  = s * (1.0f / 128.0f);
        const float var = s2 * (1.0f / 128.0f) - mu * mu;
        const float rs  = rsqrtf(var + LN_EPS);
        const int n = base + n2;
        const int dbase = seg * 16;
        float ov[16];
        #pragma unroll
        for (int j = 0; j < 16; ++j) {
            float z = (vs[j] - mu) * rs * gamma[dbase + j] + beta[dbase + j];
            ov[j] = (z > 0.0f) ? z : expm1f(z);
        }
        float4* op = (float4*)(fout + (size_t)n * DIM + dbase);
        op[0] = make_float4(ov[0],  ov[1],  ov[2],  ov[3]);
        op[1] = make_float4(ov[4],  ov[5],  ov[6],  ov[7]);
        op[2] = make_float4(ov[8],  ov[9],  ov[10], ov[11]);
        op[3] = make_float4(ov[12], ov[13], ov[14], ov[15]);
    }
}

// ---------- output gather ----------
__global__ __launch_bounds__(256) void gather_kernel(const float* __restrict__ fin,
                                                     const int* __restrict__ uid,
                                                     float* __restrict__ out) {
    int idx = blockIdx.x * 256 + threadIdx.x;   // float4 index
    int u = idx >> 5;
    int lane = idx & 31;
    if (u < N_UID) {
        int node = uid[u];
        ((float4*)out)[idx] = ((const float4*)(fin + (size_t)node * DIM))[lane];
    }
}

extern "C" void kernel_launch(void* const* d_in, const int* in_sizes, int n_in,
                              void* d_out, int out_size, void* d_ws, size_t ws_size,
                              hipStream_t stream) {
    const float* emb   = (const float*)d_in[0];
    const float* W     = (const float*)d_in[1];
    const float* bias  = (const float*)d_in[2];
    const float* gamma = (const float*)d_in[3];
    const float* beta  = (const float*)d_in[4];
    const int*   src   = (const int*)d_in[5];
    const int*   dst   = (const int*)d_in[6];
    const int*   uid   = (const int*)d_in[7];

    // workspace layout (floats/ints), ~56 MB total
    float* A   = (float*)d_ws;                       // 50000*128
    float* B   = A + (size_t)N_NODES * DIM;          // 50000*128
    float* inv = B + (size_t)N_NODES * DIM;          // 50000
    int*   cnt = (int*)(inv + N_NODES);              // 50000
    int*   off = cnt + N_NODES;                      // 50001 (+pad)
    int*   cur = off + (N_NODES + 4);                // 50000
    int*   bsum = cur + N_NODES;                     // 256
    int*   bpre = bsum + 256;                        // 256
    int*   csr  = bpre + 256;                        // 800000

    hipMemsetAsync(cnt, 0, N_NODES * sizeof(int), stream);

    const int eblk = (N_EDGES + 255) / 256;          // 3125
    const int nblk = (N_NODES + 255) / 256;          // 196
    deg_kernel<<<eblk, 256, 0, stream>>>(dst, cnt);
    inv_kernel<<<nblk, 256, 0, stream>>>(cnt, inv);
    scan1<<<nblk, 256, 0, stream>>>(cnt, off, bsum);
    scan2<<<1, 256, 0, stream>>>(bsum, bpre, nblk);
    scan3<<<nblk, 256, 0, stream>>>(off, bpre, cur);
    fill_kernel<<<eblk, 256, 0, stream>>>(src, dst, cur, csr);

    const int lblocks = N_NODES / NB;                // 3125 exact
    layer_kernel<<<lblocks, 128, 0, stream>>>(emb, A, off, csr, inv,
                                              W, bias, gamma, beta);
    layer_kernel<<<lblocks, 128, 0, stream>>>(A, B, off, csr, inv,
                                              W + DIM * DIM, bias + DIM, gamma + DIM, beta + DIM);
    layer_kernel<<<lblocks, 128, 0, stream>>>(B, A, off, csr, inv,
                                              W + 2 * DIM * DIM, bias + 2 * DIM, gamma + 2 * DIM, beta + 2 * DIM);

    gather_kernel<<<(N_UID * DIM / 4 + 255) / 256, 256, 0, stream>>>(A, uid, (float*)d_out);
}

// Round 2
// 559.557 us; speedup vs baseline: 1.0905x; 1.0905x over previous
//
#include <hip/hip_runtime.h>
#include <math.h>

#define N_NODES 50000
#define DIM     128
#define N_EDGES 800000
#define N_UID   4096
#define NB      16
#define LN_EPS  1e-5f
#define RSTRIDE 132   // padded LDS row stride (floats); 132*4=528 B, 16B-aligned

// ---------- CSR build ----------
__global__ __launch_bounds__(256) void deg_kernel(const int* __restrict__ dst, int* __restrict__ cnt) {
    int e = blockIdx.x * 256 + threadIdx.x;
    if (e < N_EDGES) atomicAdd(&cnt[dst[e]], 1);
}

__global__ __launch_bounds__(256) void scan1(const int* __restrict__ cnt, int* __restrict__ off,
                                             int* __restrict__ bsum) {
    __shared__ int sh[256];
    int t = threadIdx.x;
    int i = blockIdx.x * 256 + t;
    int v = (i < N_NODES) ? cnt[i] : 0;
    sh[t] = v;
    __syncthreads();
    for (int o = 1; o < 256; o <<= 1) {
        int x = (t >= o) ? sh[t - o] : 0;
        __syncthreads();
        sh[t] += x;
        __syncthreads();
    }
    if (i < N_NODES) off[i] = sh[t] - v;   // exclusive within block
    if (t == 255) bsum[blockIdx.x] = sh[255];
}

// adds serial block prefix (<=196 scalar loads) — replaces scan2+scan3
__global__ __launch_bounds__(256) void scan3(int* __restrict__ off, const int* __restrict__ bsum,
                                             int* __restrict__ cur) {
    __shared__ int pre;
    if (threadIdx.x == 0) {
        int s = 0;
        for (int b = 0; b < (int)blockIdx.x; ++b) s += bsum[b];
        pre = s;
    }
    __syncthreads();
    int i = blockIdx.x * 256 + threadIdx.x;
    if (i < N_NODES) {
        int o = off[i] + pre;
        off[i] = o;
        cur[i] = o;
    }
    if (i == 0) off[N_NODES] = N_EDGES;
}

__global__ __launch_bounds__(256) void fill_kernel(const int* __restrict__ src, const int* __restrict__ dst,
                                                   int* __restrict__ cur, int* __restrict__ csr) {
    int e = blockIdx.x * 256 + threadIdx.x;
    if (e < N_EDGES) {
        int p = atomicAdd(&cur[dst[e]], 1);
        csr[p] = src[e];
    }
}

// ---------- fused layer: gather-aggregate + GEMM + LN + ELU ----------
// block = 256 threads, NB=16 nodes. 50000 = 16*3125 exactly.
__global__ __launch_bounds__(256) void layer_kernel(
    const float* __restrict__ fin, float* __restrict__ fout,
    const int* __restrict__ off, const int* __restrict__ csr,
    const float* __restrict__ W, const float* __restrict__ bias,
    const float* __restrict__ gamma, const float* __restrict__ beta)
{
    __shared__ float us[NB * RSTRIDE];   // holds x (aggregated), later reused for y
    const int t = threadIdx.x;
    const int base = blockIdx.x * NB;

    // ---- phase 1: aggregate (self + neigh) * inv into us ----
    {
        const int lane32 = t & 31;       // float4 index within 512B row
        const int stream = t >> 5;       // 0..7 concurrent node streams
        #pragma unroll
        for (int rep = 0; rep < 2; ++rep) {
            const int slot = rep * 8 + stream;
            const int n = base + slot;
            const int e0 = off[n], e1 = off[n + 1];
            const int deg = e1 - e0;
            const int* __restrict__ brow = csr + e0;
            float4 acc = ((const float4*)(fin + (size_t)n * DIM))[lane32];
            int e = 0;
            for (; e + 4 <= deg; e += 4) {
                const int s0 = brow[e + 0];
                const int s1 = brow[e + 1];
                const int s2 = brow[e + 2];
                const int s3 = brow[e + 3];
                const float4 v0 = ((const float4*)(fin + (size_t)s0 * DIM))[lane32];
                const float4 v1 = ((const float4*)(fin + (size_t)s1 * DIM))[lane32];
                const float4 v2 = ((const float4*)(fin + (size_t)s2 * DIM))[lane32];
                const float4 v3 = ((const float4*)(fin + (size_t)s3 * DIM))[lane32];
                acc.x += (v0.x + v1.x) + (v2.x + v3.x);
                acc.y += (v0.y + v1.y) + (v2.y + v3.y);
                acc.z += (v0.z + v1.z) + (v2.z + v3.z);
                acc.w += (v0.w + v1.w) + (v2.w + v3.w);
            }
            for (; e < deg; ++e) {
                const int s = brow[e];
                const float4 v = ((const float4*)(fin + (size_t)s * DIM))[lane32];
                acc.x += v.x; acc.y += v.y; acc.z += v.z; acc.w += v.w;
            }
            const float iv = 1.0f / (float)(deg + 1);
            acc.x *= iv; acc.y *= iv; acc.z *= iv; acc.w *= iv;
            ((float4*)(us + slot * RSTRIDE))[lane32] = acc;
        }
    }
    __syncthreads();

    // ---- phase 2: y[j][c] = dot(W[c,:], x[j,:]) + b[c] ----
    // thread t: column c = t&127, node half h = t>>7 (nodes h*8 .. h*8+7)
    float acc[8];
    const int c = t & 127;
    const int h = t >> 7;
    {
        const float bv = bias[c];
        #pragma unroll
        for (int j = 0; j < 8; ++j) acc[j] = bv;
        const float4* __restrict__ Wr = (const float4*)(W + (size_t)c * DIM);
        const float* __restrict__ xb = us + h * 8 * RSTRIDE;
        for (int k4 = 0; k4 < DIM / 4; ++k4) {
            const float4 w = Wr[k4];
            #pragma unroll
            for (int j = 0; j < 8; ++j) {
                const float4 xv = *((const float4*)(xb + j * RSTRIDE + k4 * 4)); // wave-uniform broadcast
                acc[j] = fmaf(w.x, xv.x, acc[j]);
                acc[j] = fmaf(w.y, xv.y, acc[j]);
                acc[j] = fmaf(w.z, xv.z, acc[j]);
                acc[j] = fmaf(w.w, xv.w, acc[j]);
            }
        }
    }
    __syncthreads();   // all x reads done before overwriting us with y
    {
        #pragma unroll
        for (int j = 0; j < 8; ++j) us[(h * 8 + j) * RSTRIDE + c] = acc[j];
    }
    __syncthreads();

    // ---- phase 3: LayerNorm + ELU; 16 threads per node, 8 dims each ----
    {
        const int j   = t >> 4;          // node 0..15
        const int seg = t & 15;          // 0..15
        const float* yr = us + j * RSTRIDE + seg * 8;
        const float4 a0 = ((const float4*)yr)[0];
        const float4 a1 = ((const float4*)yr)[1];
        float vs[8] = {a0.x, a0.y, a0.z, a0.w, a1.x, a1.y, a1.z, a1.w};
        float s = 0.0f, s2 = 0.0f;
        #pragma unroll
        for (int i = 0; i < 8; ++i) { s += vs[i]; s2 += vs[i] * vs[i]; }
        #pragma unroll
        for (int m = 1; m < 16; m <<= 1) {
            s  += __shfl_xor(s,  m);
            s2 += __shfl_xor(s2, m);
        }
        const float mu  = s * (1.0f / 128.0f);
        const float var = s2 * (1.0f / 128.0f) - mu * mu;
        const float rs  = rsqrtf(var + LN_EPS);
        const int n  = base + j;
        const int db = seg * 8;
        float ov[8];
        #pragma unroll
        for (int i = 0; i < 8; ++i) {
            const float z = (vs[i] - mu) * rs * gamma[db + i] + beta[db + i];
            ov[i] = (z > 0.0f) ? z : expm1f(z);
        }
        float4* op = (float4*)(fout + (size_t)n * DIM + db);
        op[0] = make_float4(ov[0], ov[1], ov[2], ov[3]);
        op[1] = make_float4(ov[4], ov[5], ov[6], ov[7]);
    }
}

// ---------- output gather ----------
__global__ __launch_bounds__(256) void gather_kernel(const float* __restrict__ fin,
                                                     const int* __restrict__ uid,
                                                     float* __restrict__ out) {
    int idx = blockIdx.x * 256 + threadIdx.x;   // float4 index
    int u = idx >> 5;
    int lane = idx & 31;
    if (u < N_UID) {
        int node = uid[u];
        ((float4*)out)[idx] = ((const float4*)(fin + (size_t)node * DIM))[lane];
    }
}

extern "C" void kernel_launch(void* const* d_in, const int* in_sizes, int n_in,
                              void* d_out, int out_size, void* d_ws, size_t ws_size,
                              hipStream_t stream) {
    const float* emb   = (const float*)d_in[0];
    const float* W     = (const float*)d_in[1];
    const float* bias  = (const float*)d_in[2];
    const float* gamma = (const float*)d_in[3];
    const float* beta  = (const float*)d_in[4];
    const int*   src   = (const int*)d_in[5];
    const int*   dst   = (const int*)d_in[6];
    const int*   uid   = (const int*)d_in[7];

    // workspace layout (~55 MB)
    float* A    = (float*)d_ws;                      // 50000*128
    float* B    = A + (size_t)N_NODES * DIM;         // 50000*128
    int*   cnt  = (int*)(B + (size_t)N_NODES * DIM); // 50000
    int*   off  = cnt + N_NODES;                     // 50001 (+pad)
    int*   cur  = off + (N_NODES + 4);               // 50000
    int*   bsum = cur + N_NODES;                     // 256
    int*   csr  = bsum + 256;                        // 800000

    hipMemsetAsync(cnt, 0, N_NODES * sizeof(int), stream);

    const int eblk = (N_EDGES + 255) / 256;          // 3125
    const int nblk = (N_NODES + 255) / 256;          // 196
    deg_kernel<<<eblk, 256, 0, stream>>>(dst, cnt);
    scan1<<<nblk, 256, 0, stream>>>(cnt, off, bsum);
    scan3<<<nblk, 256, 0, stream>>>(off, bsum, cur);
    fill_kernel<<<eblk, 256, 0, stream>>>(src, dst, cur, csr);

    const int lblocks = N_NODES / NB;                // 3125 exact
    layer_kernel<<<lblocks, 256, 0, stream>>>(emb, A, off, csr,
                                              W, bias, gamma, beta);
    layer_kernel<<<lblocks, 256, 0, stream>>>(A, B, off, csr,
                                              W + DIM * DIM, bias + DIM, gamma + DIM, beta + DIM);
    layer_kernel<<<lblocks, 256, 0, stream>>>(B, A, off, csr,
                                              W + 2 * DIM * DIM, bias + 2 * DIM, gamma + 2 * DIM, beta + 2 * DIM);

    gather_kernel<<<(N_UID * DIM / 4 + 255) / 256, 256, 0, stream>>>(A, uid, (float*)d_out);
}